// Round 12
// baseline (175.904 us; speedup 1.0000x reference)
//
#include <hip/hip_runtime.h>
#include <hip/hip_bf16.h>

// L=4096, B=16, C_IN=512, C_OUT=512, C_COND=512, K=4, HID=128, T=30
typedef __bf16 bfx8 __attribute__((ext_vector_type(8)));
typedef float f32x4 __attribute__((ext_vector_type(4)));
typedef float f32x8v __attribute__((ext_vector_type(8)));
typedef unsigned short u16x8 __attribute__((ext_vector_type(8)));
typedef unsigned short u16x4 __attribute__((ext_vector_type(4)));

__device__ __forceinline__ unsigned short f2bf(float f) {
    unsigned int u = __builtin_bit_cast(unsigned int, f);
    u += 0x7fffu + ((u >> 16) & 1u);          // RNE
    return (unsigned short)(u >> 16);
}

__device__ __forceinline__ bfx8 cvt8(float4 a, float4 b) {
    f32x8v v = {a.x, a.y, a.z, a.w, b.x, b.y, b.z, b.w};
    return __builtin_convertvector(v, bfx8);   // v_cvt_pk_bf16_f32 chain (RNE)
}

// ---------- kernel 1: conditioning MLP. One block per b. ----------
__global__ __launch_bounds__(1024) void att_kernel(
    const float* __restrict__ cond, const float* __restrict__ fc1w,
    const float* __restrict__ fc1b, const float* __restrict__ fc2w,
    const float* __restrict__ fc2b, const float* __restrict__ bias,
    float* __restrict__ att_out, float* __restrict__ bagg_out)
{
    __shared__ float h[128];
    __shared__ float att_s[4];
    const int b    = blockIdx.x;
    const int tid  = threadIdx.x;
    const int lane = tid & 63;
    const int wv   = tid >> 6;          // 0..15

    for (int j = wv; j < 128; j += 16) {
        const float* c = cond + b * 512 + lane * 8;
        const float* w = fc1w + j * 512 + lane * 8;
        const float4 c0 = *(const float4*)c, c1 = *(const float4*)(c + 4);
        const float4 w0 = *(const float4*)w, w1 = *(const float4*)(w + 4);
        float s = c0.x * w0.x + c0.y * w0.y + c0.z * w0.z + c0.w * w0.w
                + c1.x * w1.x + c1.y * w1.y + c1.z * w1.z + c1.w * w1.w;
        #pragma unroll
        for (int off = 32; off; off >>= 1) s += __shfl_down(s, off);
        if (lane == 0) h[j] = fmaxf(s + fc1b[j], 0.0f);
    }
    __syncthreads();

    if (wv < 4) {
        const int k = wv;
        float s = h[lane] * fc2w[k * 128 + lane] + h[lane + 64] * fc2w[k * 128 + lane + 64];
        #pragma unroll
        for (int off = 32; off; off >>= 1) s += __shfl_down(s, off);
        if (lane == 0) att_s[k] = (s + fc2b[k]) * (1.0f / 30.0f);
    }
    __syncthreads();

    if (tid == 0) {
        float l0 = att_s[0], l1 = att_s[1], l2 = att_s[2], l3 = att_s[3];
        float m = fmaxf(fmaxf(l0, l1), fmaxf(l2, l3));
        float e0 = expf(l0 - m), e1 = expf(l1 - m), e2 = expf(l2 - m), e3 = expf(l3 - m);
        float inv = 1.0f / (e0 + e1 + e2 + e3);
        att_s[0] = e0 * inv; att_s[1] = e1 * inv; att_s[2] = e2 * inv; att_s[3] = e3 * inv;
        att_out[b * 4 + 0] = att_s[0]; att_out[b * 4 + 1] = att_s[1];
        att_out[b * 4 + 2] = att_s[2]; att_out[b * 4 + 3] = att_s[3];
    }
    __syncthreads();

    if (tid < 512) {
        bagg_out[b * 512 + tid] = att_s[0] * bias[tid] + att_s[1] * bias[512 + tid]
                                + att_s[2] * bias[1024 + tid] + att_s[3] * bias[1536 + tid];
    }
}

// ---------- kernel 2: w_agg[b][o][i] = sum_k att[b][k]*weight[k][o][i], bf16 ----------
__global__ __launch_bounds__(256) void wagg_kernel(
    const float* __restrict__ weight, const float* __restrict__ att,
    unsigned short* __restrict__ wagg)
{
    __shared__ float a_s[64];
    if (threadIdx.x < 64) a_s[threadIdx.x] = att[threadIdx.x];
    __syncthreads();
    const int p = (blockIdx.x * 256 + threadIdx.x) * 4;
    const float4 w0 = *(const float4*)(weight + p);
    const float4 w1 = *(const float4*)(weight + 262144 + p);
    const float4 w2 = *(const float4*)(weight + 524288 + p);
    const float4 w3 = *(const float4*)(weight + 786432 + p);
    #pragma unroll
    for (int b = 0; b < 16; ++b) {
        const float a0 = a_s[4 * b], a1 = a_s[4 * b + 1], a2 = a_s[4 * b + 2], a3 = a_s[4 * b + 3];
        u16x4 r;
        r[0] = f2bf(a0 * w0.x + a1 * w1.x + a2 * w2.x + a3 * w3.x);
        r[1] = f2bf(a0 * w0.y + a1 * w1.y + a2 * w2.y + a3 * w3.y);
        r[2] = f2bf(a0 * w0.z + a1 * w1.z + a2 * w2.z + a3 * w3.z);
        r[3] = f2bf(a0 * w0.w + a1 * w1.w + a2 * w2.w + a3 * w3.w);
        *(u16x4*)(wagg + (size_t)b * 262144 + p) = r;
    }
}

// ---------- kernel 3: W-resident-LDS, barrier-free K-loop ----------
// Block: 512 thr = 8 waves (4m x 2n). Output 512L x 128o per block; wave 128L x 64o,
// acc 8x4. W slice [128 o][512 K] bf16 = 128 KB pinned in LDS (full K, staged ONCE).
// A (x) is loaded DIRECTLY global->reg each K-step (fp32 -> bf16 cvt_pk), 1-step
// prefetch. K-loop has NO barriers / NO glds / NO ds_writes: waves run free,
// 2 waves/SIMD cover each other's latency. W swizzle: chunk c^(row&7) within each
// 8-chunk group; glds linear dest + pre-swizzled source (rule 21).
// Grid 512 = 16b x 4nt x 8lg, XCD-chunked (cpx=64): same-b families per XCD.
__global__ __launch_bounds__(512, 2) void gemm_kernel(
    const float* __restrict__ x, const unsigned short* __restrict__ wagg,
    const float* __restrict__ bagg, float* __restrict__ out)
{
    __shared__ unsigned short Ws[128 * 512];   // 128 KB

    const int tid = threadIdx.x;
    // XCD swizzle: nwg=512, nxcd=8, cpx=64 (bijective)
    const int wgid = (blockIdx.x & 7) * 64 + (blockIdx.x >> 3);
    const int fam  = wgid >> 3;          // 0..63 = b*4 + nt
    const int lg   = wgid & 7;           // L chunk
    const int b    = fam >> 2;
    const int nt   = fam & 3;
    const int l0   = lg * 512;
    const int n0   = nt * 128;

    const int lane = tid & 63;
    const int wid  = tid >> 6;           // 0..7
    const int wm   = wid >> 1;           // 0..3 (L quarter)
    const int wn   = wid & 1;            // 0..1 (o half)
    const int fr   = lane & 15;
    const int fq   = lane >> 4;

    const unsigned short* wb = wagg + (size_t)b * 262144 + (size_t)n0 * 512;

    // ---- prologue: stage W slice into LDS (pre-swizzled source, linear dest) ----
    #pragma unroll
    for (int it = 0; it < 16; ++it) {
        const int s   = it * 512 + tid;       // 16B chunk slot, 0..8191
        const int row = s >> 6;               // o row 0..127
        const int cd  = s & 63;               // dest chunk in row
        const int csrc = (cd & ~7) | ((cd & 7) ^ (row & 7));
        char* dst = (char*)Ws + s * 16;
        __builtin_amdgcn_global_load_lds(
            (const __attribute__((address_space(1))) void*)(wb + row * 512 + csrc * 8),
            (__attribute__((address_space(3))) void*)dst, 16, 0, 0);
    }

    // A addressing: row = l0 + wm*128 + mf*16 + fr; k = kt*32 + fq*8
    const float* xbase = x + ((size_t)(l0 + wm * 128 + fr) * 16 + b) * 512 + fq * 8;

    // B (W) LDS read: base per nf; per-kt swizzled chunk offset (same for all nf)
    int bbase[4];
    #pragma unroll
    for (int nf = 0; nf < 4; ++nf) bbase[nf] = (wn * 64 + nf * 16 + fr) * 512;
    const int r7 = fr & 7;

    f32x4 acc[8][4];
    #pragma unroll
    for (int i = 0; i < 8; ++i)
        #pragma unroll
        for (int j = 0; j < 4; ++j) acc[i][j] = f32x4{0.f, 0.f, 0.f, 0.f};

    // prefetch x for kt=0
    float4 xp[16];
    #pragma unroll
    for (int mf = 0; mf < 8; ++mf) {
        const float* p = xbase + (size_t)mf * 16 * 8192;
        xp[2 * mf]     = *(const float4*)(p);
        xp[2 * mf + 1] = *(const float4*)(p + 4);
    }

    __syncthreads();   // W staged (drains glds + x loads; prologue only)

    for (int kt = 0; kt < 16; ++kt) {
        // W fragments for this K-step (swizzled chunk; identical offset all nf)
        const int koff = ((kt >> 1) * 8 + (((kt & 1) * 4 + fq) ^ r7)) * 8;
        bfx8 bfr[4];
        #pragma unroll
        for (int nf = 0; nf < 4; ++nf)
            bfr[nf] = *reinterpret_cast<const bfx8*>(&Ws[bbase[nf] + koff]);
        // issue next-step x loads (independent; in flight under MFMA)
        float4 xn[16];
        if (kt < 15) {
            const int ko = (kt + 1) * 32;
            #pragma unroll
            for (int mf = 0; mf < 8; ++mf) {
                const float* p = xbase + (size_t)mf * 16 * 8192 + ko;
                xn[2 * mf]     = *(const float4*)(p);
                xn[2 * mf + 1] = *(const float4*)(p + 4);
            }
        }
        // convert current x and MFMA
        #pragma unroll
        for (int mf = 0; mf < 8; ++mf) {
            const bfx8 afr = cvt8(xp[2 * mf], xp[2 * mf + 1]);
            #pragma unroll
            for (int nf = 0; nf < 4; ++nf)
                acc[mf][nf] = __builtin_amdgcn_mfma_f32_16x16x32_bf16(afr, bfr[nf], acc[mf][nf], 0, 0, 0);
        }
        if (kt < 15) {
            #pragma unroll
            for (int j = 0; j < 16; ++j) xp[j] = xn[j];
        }
    }

    // ---- epilogue: C/D map col=lane&15 (o), row=(lane>>4)*4+r (L) ----
    #pragma unroll
    for (int nf = 0; nf < 4; ++nf) {
        const int on = wn * 64 + nf * 16 + fr;
        const float bb = bagg[b * 512 + n0 + on];
        #pragma unroll
        for (int mf = 0; mf < 8; ++mf) {
            const int lrow = l0 + wm * 128 + mf * 16 + fq * 4;
            float* op = out + ((size_t)lrow * 16 + b) * 512 + n0 + on;
            const f32x4 a = acc[mf][nf];
            op[0]        = a[0] + bb;
            op[8192]     = a[1] + bb;
            op[2 * 8192] = a[2] + bb;
            op[3 * 8192] = a[3] + bb;
        }
    }
}

extern "C" void kernel_launch(void* const* d_in, const int* in_sizes, int n_in,
                              void* d_out, int out_size, void* d_ws, size_t ws_size,
                              hipStream_t stream) {
    const float* x      = (const float*)d_in[0];
    const float* cond   = (const float*)d_in[1];
    const float* fc1w   = (const float*)d_in[2];
    const float* fc1b   = (const float*)d_in[3];
    const float* fc2w   = (const float*)d_in[4];
    const float* fc2b   = (const float*)d_in[5];
    const float* weight = (const float*)d_in[6];
    const float* bias   = (const float*)d_in[7];
    float* out = (float*)d_out;

    char* ws = (char*)d_ws;
    float* att_ws  = (float*)ws;                       // 64 f32
    float* bagg_ws = (float*)(ws + 1024);              // 8192 f32
    unsigned short* wagg_ws = (unsigned short*)(ws + 65536);  // 8 MiB bf16

    att_kernel<<<16, 1024, 0, stream>>>(cond, fc1w, fc1b, fc2w, fc2b, bias, att_ws, bagg_ws);
    wagg_kernel<<<256, 256, 0, stream>>>(weight, att_ws, wagg_ws);
    gemm_kernel<<<512, 512, 0, stream>>>(x, wagg_ws, bagg_ws, out);
}

// Round 13
// 112.326 us; speedup vs baseline: 1.5660x; 1.5660x over previous
//
#include <hip/hip_runtime.h>
#include <hip/hip_bf16.h>

// L=4096, B=16, C_IN=512, C_OUT=512, C_COND=512, K=4, HID=128, T=30
typedef __bf16 bfx8 __attribute__((ext_vector_type(8)));
typedef float f32x4 __attribute__((ext_vector_type(4)));
typedef unsigned short u16x8 __attribute__((ext_vector_type(8)));
typedef unsigned short u16x4 __attribute__((ext_vector_type(4)));

__device__ __forceinline__ unsigned short f2bf(float f) {
    unsigned int u = __builtin_bit_cast(unsigned int, f);
    u += 0x7fffu + ((u >> 16) & 1u);          // RNE
    return (unsigned short)(u >> 16);
}

// ---------- kernel 1: conditioning MLP. One block per b. ----------
__global__ __launch_bounds__(1024) void att_kernel(
    const float* __restrict__ cond, const float* __restrict__ fc1w,
    const float* __restrict__ fc1b, const float* __restrict__ fc2w,
    const float* __restrict__ fc2b, const float* __restrict__ bias,
    float* __restrict__ att_out, float* __restrict__ bagg_out)
{
    __shared__ float h[128];
    __shared__ float att_s[4];
    const int b    = blockIdx.x;
    const int tid  = threadIdx.x;
    const int lane = tid & 63;
    const int wv   = tid >> 6;          // 0..15

    for (int j = wv; j < 128; j += 16) {
        const float* c = cond + b * 512 + lane * 8;
        const float* w = fc1w + j * 512 + lane * 8;
        const float4 c0 = *(const float4*)c, c1 = *(const float4*)(c + 4);
        const float4 w0 = *(const float4*)w, w1 = *(const float4*)(w + 4);
        float s = c0.x * w0.x + c0.y * w0.y + c0.z * w0.z + c0.w * w0.w
                + c1.x * w1.x + c1.y * w1.y + c1.z * w1.z + c1.w * w1.w;
        #pragma unroll
        for (int off = 32; off; off >>= 1) s += __shfl_down(s, off);
        if (lane == 0) h[j] = fmaxf(s + fc1b[j], 0.0f);
    }
    __syncthreads();

    if (wv < 4) {
        const int k = wv;
        float s = h[lane] * fc2w[k * 128 + lane] + h[lane + 64] * fc2w[k * 128 + lane + 64];
        #pragma unroll
        for (int off = 32; off; off >>= 1) s += __shfl_down(s, off);
        if (lane == 0) att_s[k] = (s + fc2b[k]) * (1.0f / 30.0f);
    }
    __syncthreads();

    if (tid == 0) {
        float l0 = att_s[0], l1 = att_s[1], l2 = att_s[2], l3 = att_s[3];
        float m = fmaxf(fmaxf(l0, l1), fmaxf(l2, l3));
        float e0 = expf(l0 - m), e1 = expf(l1 - m), e2 = expf(l2 - m), e3 = expf(l3 - m);
        float inv = 1.0f / (e0 + e1 + e2 + e3);
        att_s[0] = e0 * inv; att_s[1] = e1 * inv; att_s[2] = e2 * inv; att_s[3] = e3 * inv;
        att_out[b * 4 + 0] = att_s[0]; att_out[b * 4 + 1] = att_s[1];
        att_out[b * 4 + 2] = att_s[2]; att_out[b * 4 + 3] = att_s[3];
    }
    __syncthreads();

    if (tid < 512) {
        bagg_out[b * 512 + tid] = att_s[0] * bias[tid] + att_s[1] * bias[512 + tid]
                                + att_s[2] * bias[1024 + tid] + att_s[3] * bias[1536 + tid];
    }
}

// ---------- kernel 2: w_agg[b][o][i] = sum_k att[b][k]*weight[k][o][i], bf16 ----------
__global__ __launch_bounds__(256) void wagg_kernel(
    const float* __restrict__ weight, const float* __restrict__ att,
    unsigned short* __restrict__ wagg)
{
    __shared__ float a_s[64];
    if (threadIdx.x < 64) a_s[threadIdx.x] = att[threadIdx.x];
    __syncthreads();
    const int p = (blockIdx.x * 256 + threadIdx.x) * 4;
    const float4 w0 = *(const float4*)(weight + p);
    const float4 w1 = *(const float4*)(weight + 262144 + p);
    const float4 w2 = *(const float4*)(weight + 524288 + p);
    const float4 w3 = *(const float4*)(weight + 786432 + p);
    #pragma unroll
    for (int b = 0; b < 16; ++b) {
        const float a0 = a_s[4 * b], a1 = a_s[4 * b + 1], a2 = a_s[4 * b + 2], a3 = a_s[4 * b + 3];
        u16x4 r;
        r[0] = f2bf(a0 * w0.x + a1 * w1.x + a2 * w2.x + a3 * w3.x);
        r[1] = f2bf(a0 * w0.y + a1 * w1.y + a2 * w2.y + a3 * w3.y);
        r[2] = f2bf(a0 * w0.z + a1 * w1.z + a2 * w2.z + a3 * w3.z);
        r[3] = f2bf(a0 * w0.w + a1 * w1.w + a2 * w2.w + a3 * w3.w);
        *(u16x4*)(wagg + (size_t)b * 262144 + p) = r;
    }
}

// ---------- kernel 3: 8-phase schedule, T4-COUNTED (the R11 fix) ----------
// BM=256, BN=256, BK=64 (8 K-tiles). 512 thr = 8 waves (2m x 4n), wave 128x64.
// As dbuf (2x32KB) + Bs TRIPLE buffer (3x32KB) = 160 KB LDS exactly.
// B(t+2) issued at P1 of t; P3 tail waits vmcnt(4): B(t+1) drained (oldest),
// B(t+2) stays in flight across the tile boundary. Never drain-0 mid-loop
// (t==6 tail only). x(t+1): issue P0, convert+write P3 (T14). bagg read direct.
__global__ __launch_bounds__(512, 2) void gemm_kernel(
    const float* __restrict__ x, const unsigned short* __restrict__ wagg,
    const float* __restrict__ bagg, float* __restrict__ out)
{
    __shared__ unsigned short As[2][256 * 64];   // 64 KB
    __shared__ unsigned short Bs[3][256 * 64];   // 96 KB

    const int tid = threadIdx.x;
    // XCD swizzle: nwg=512, nxcd=8, cpx=64 (bijective)
    const int bid = (blockIdx.x & 7) * 64 + (blockIdx.x >> 3);
    const int b  = bid >> 5;          // 0..15
    const int lt = (bid >> 1) & 15;   // L tile (256 rows)
    const int nt = bid & 1;           // N tile
    const int l0 = lt * 256;
    const int n0 = nt * 256;

    const int lane = tid & 63;
    const int wid  = tid >> 6;        // 0..7
    const int wm   = wid >> 2;        // 0..1
    const int wn   = wid & 3;         // 0..3
    const int fr   = lane & 15;
    const int fq   = lane >> 4;

    const unsigned short* wb = wagg + (size_t)b * (512 * 512) + (size_t)n0 * 512;

    f32x4 acc[8][4];
    #pragma unroll
    for (int i = 0; i < 8; ++i)
        #pragma unroll
        for (int j = 0; j < 4; ++j) acc[i][j] = f32x4{0.f, 0.f, 0.f, 0.f};

    // --- A staging geometry: row=tid>>1, cols (tid&1)*32..+32 (4 chunks of 8 bf16)
    const int arow = tid >> 1;
    const int ach  = (tid & 1) * 4;
    const float* xsrc = x + ((size_t)(l0 + arow) * 16 + b) * 512 + (tid & 1) * 32;
    int awr[4];
    #pragma unroll
    for (int j = 0; j < 4; ++j)
        awr[j] = arow * 64 + (((ach + j) ^ (arow & 7)) << 3);

    // --- B staging: linear glds dest chunk s <- pre-swizzled source (rule 21)
    int bofs[4], bdst[4];
    #pragma unroll
    for (int it = 0; it < 4; ++it) {
        const int s  = it * 512 + tid;
        const int rw = s >> 3, cd = s & 7;
        const int cs = cd ^ (rw & 7);
        bofs[it] = rw * 512 + cs * 8;
        bdst[it] = s * 16;
    }

    // --- fragment read address components (loop-invariant)
    int abase[8], bbase[4], koff[2];
    #pragma unroll
    for (int mf = 0; mf < 8; ++mf) abase[mf] = (wm * 128 + mf * 16 + fr) * 64;
    #pragma unroll
    for (int nf = 0; nf < 4; ++nf) bbase[nf] = (wn * 64 + nf * 16 + fr) * 64;
    #pragma unroll
    for (int ks = 0; ks < 2; ++ks) koff[ks] = (((ks * 4 + fq) ^ (fr & 7)) << 3);

    // --- prologue: B(0)->Bs0, B(1)->Bs1, A(0)->As0; counted drain vmcnt(4) ---
    {
        #pragma unroll
        for (int it = 0; it < 4; ++it) {
            char* dst = (char*)&Bs[0][0] + bdst[it];
            __builtin_amdgcn_global_load_lds(
                (const __attribute__((address_space(1))) void*)(wb + bofs[it]),
                (__attribute__((address_space(3))) void*)dst, 16, 0, 0);
        }
        #pragma unroll
        for (int it = 0; it < 4; ++it) {
            char* dst = (char*)&Bs[1][0] + bdst[it];
            __builtin_amdgcn_global_load_lds(
                (const __attribute__((address_space(1))) void*)(wb + bofs[it] + 64),
                (__attribute__((address_space(3))) void*)dst, 16, 0, 0);
        }
        float4 v[8];
        #pragma unroll
        for (int j = 0; j < 8; ++j) v[j] = *(const float4*)(xsrc + j * 4);
        #pragma unroll
        for (int j = 0; j < 4; ++j) {
            u16x8 pk;
            pk[0] = f2bf(v[2*j].x);   pk[1] = f2bf(v[2*j].y);
            pk[2] = f2bf(v[2*j].z);   pk[3] = f2bf(v[2*j].w);
            pk[4] = f2bf(v[2*j+1].x); pk[5] = f2bf(v[2*j+1].y);
            pk[6] = f2bf(v[2*j+1].z); pk[7] = f2bf(v[2*j+1].w);
            *(u16x8*)&As[0][awr[j]] = pk;
        }
        // x(0) drained by the converts above; B(0) done at vmcnt(4); B(1) in flight
        asm volatile("s_waitcnt vmcnt(4) lgkmcnt(0)" ::: "memory");
        __builtin_amdgcn_s_barrier();
    }

// One phase: quadrant (MQ,NQ): 8 A + 4 B ds_reads, barrier, lgkm(0), 16 MFMA.
#define PHASE(MQ, NQ, TAIL_ASM)                                                   \
    do {                                                                          \
        const unsigned short* Ac = &As[acur][0];                                  \
        const unsigned short* Bc = &Bs[bcur][0];                                  \
        bfx8 afr[4][2], bfr[2][2];                                                \
        _Pragma("unroll")                                                         \
        for (int i = 0; i < 4; ++i)                                               \
            _Pragma("unroll")                                                     \
            for (int ks = 0; ks < 2; ++ks)                                        \
                afr[i][ks] = *(const bfx8*)&Ac[abase[(MQ)*4 + i] + koff[ks]];     \
        _Pragma("unroll")                                                         \
        for (int j = 0; j < 2; ++j)                                               \
            _Pragma("unroll")                                                     \
            for (int ks = 0; ks < 2; ++ks)                                        \
                bfr[j][ks] = *(const bfx8*)&Bc[bbase[(NQ)*2 + j] + koff[ks]];     \
        __builtin_amdgcn_s_barrier();                                             \
        asm volatile("s_waitcnt lgkmcnt(0)" ::: "memory");                        \
        __builtin_amdgcn_sched_barrier(0);                                        \
        __builtin_amdgcn_s_setprio(1);                                            \
        _Pragma("unroll")                                                         \
        for (int ks = 0; ks < 2; ++ks)                                            \
            _Pragma("unroll")                                                     \
            for (int i = 0; i < 4; ++i)                                           \
                _Pragma("unroll")                                                 \
                for (int j = 0; j < 2; ++j)                                       \
                    acc[(MQ)*4 + i][(NQ)*2 + j] =                                 \
                        __builtin_amdgcn_mfma_f32_16x16x32_bf16(                  \
                            afr[i][ks], bfr[j][ks],                               \
                            acc[(MQ)*4 + i][(NQ)*2 + j], 0, 0, 0);                \
        __builtin_amdgcn_s_setprio(0);                                            \
        TAIL_ASM;                                                                 \
        __builtin_amdgcn_s_barrier();                                             \
    } while (0)

    for (int t = 0; t < 8; ++t) {
        const int acur = t & 1;
        const int bcur = t % 3;
        const int anxt = acur ^ 1;
        float4 xv[8];
        // ---- P0: issue x(t+1) loads; quadrant (0,0) ----
        if (t < 7) {
            const int ko = (t + 1) * 64;
            #pragma unroll
            for (int j = 0; j < 8; ++j) xv[j] = *(const float4*)(xsrc + ko + j * 4);
            __builtin_amdgcn_sched_barrier(0);
        }
        PHASE(0, 0, );
        // ---- P1: issue B glds for t+2 into Bs[(t+2)%3]; quadrant (0,1) ----
        if (t < 6) {
            const int ko = (t + 2) * 64;
            char* bb2 = (char*)&Bs[(t + 2) % 3][0];
            #pragma unroll
            for (int it = 0; it < 4; ++it) {
                __builtin_amdgcn_global_load_lds(
                    (const __attribute__((address_space(1))) void*)(wb + bofs[it] + ko),
                    (__attribute__((address_space(3))) void*)(bb2 + bdst[it]), 16, 0, 0);
            }
            __builtin_amdgcn_sched_barrier(0);
        }
        PHASE(0, 1, );
        // ---- P2: quadrant (1,0) ----
        PHASE(1, 0, );
        // ---- P3: write A(t+1); quadrant (1,1); COUNTED tail wait ----
        if (t < 7) {
            #pragma unroll
            for (int j = 0; j < 4; ++j) {
                u16x8 pk;
                pk[0] = f2bf(xv[2*j].x);   pk[1] = f2bf(xv[2*j].y);
                pk[2] = f2bf(xv[2*j].z);   pk[3] = f2bf(xv[2*j].w);
                pk[4] = f2bf(xv[2*j+1].x); pk[5] = f2bf(xv[2*j+1].y);
                pk[6] = f2bf(xv[2*j+1].z); pk[7] = f2bf(xv[2*j+1].w);
                *(u16x8*)&As[anxt][awr[j]] = pk;
            }
            __builtin_amdgcn_sched_barrier(0);
        }
        if (t < 6) {
            // B(t+1) (oldest 4) must land; B(t+2)'s 4 stay in flight
            PHASE(1, 1, asm volatile("s_waitcnt vmcnt(4)" ::: "memory"));
        } else if (t == 6) {
            // no newer loads exist; force B(7)
            PHASE(1, 1, asm volatile("s_waitcnt vmcnt(0)" ::: "memory"));
        } else {
            PHASE(1, 1, );
        }
    }
#undef PHASE

    // --- epilogue: C/D map col=lane&15 (n), row=(lane>>4)*4+r (m); bagg direct ---
    #pragma unroll
    for (int nf = 0; nf < 4; ++nf) {
        const int on = wn * 64 + nf * 16 + fr;
        const float bb = bagg[b * 512 + n0 + on];
        #pragma unroll
        for (int mf = 0; mf < 8; ++mf) {
            const int lrow = l0 + wm * 128 + mf * 16 + fq * 4;
            float* op = out + ((size_t)lrow * 16 + b) * 512 + n0 + on;
            const f32x4 a = acc[mf][nf];
            op[0]        = a[0] + bb;
            op[8192]     = a[1] + bb;
            op[2 * 8192] = a[2] + bb;
            op[3 * 8192] = a[3] + bb;
        }
    }
}

extern "C" void kernel_launch(void* const* d_in, const int* in_sizes, int n_in,
                              void* d_out, int out_size, void* d_ws, size_t ws_size,
                              hipStream_t stream) {
    const float* x      = (const float*)d_in[0];
    const float* cond   = (const float*)d_in[1];
    const float* fc1w   = (const float*)d_in[2];
    const float* fc1b   = (const float*)d_in[3];
    const float* fc2w   = (const float*)d_in[4];
    const float* fc2b   = (const float*)d_in[5];
    const float* weight = (const float*)d_in[6];
    const float* bias   = (const float*)d_in[7];
    float* out = (float*)d_out;

    char* ws = (char*)d_ws;
    float* att_ws  = (float*)ws;                       // 64 f32
    float* bagg_ws = (float*)(ws + 1024);              // 8192 f32
    unsigned short* wagg_ws = (unsigned short*)(ws + 65536);  // 8 MiB bf16

    att_kernel<<<16, 1024, 0, stream>>>(cond, fc1w, fc1b, fc2w, fc2b, bias, att_ws, bagg_ws);
    wagg_kernel<<<256, 256, 0, stream>>>(weight, att_ws, wagg_ws);
    gemm_kernel<<<512, 512, 0, stream>>>(x, wagg_ws, bagg_ws, out);
}